// Round 2
// baseline (801.817 us; speedup 1.0000x reference)
//
#include <hip/hip_runtime.h>
#include <math.h>

// Program interpreter: B=1M rows, 19 steps of MLP(2->64->64->3) + argmax walk.
// fp32 emulated on f16 MFMA, 2-limb splits (lo limb scaled 2^12, RTZ pack).
//
// R10: register-amortized multi-stream. R9 taught: DS-reduce latency was
// already hidden, and extra VALU ops cost real time -> kernel is latency-bound
// at 2 waves/SIMD, where each wave duplicates ~160 regs of identical weight
// tables for only 16 rows. Fix: ONE wave per SIMD (64-thread blocks,
// __launch_bounds__(64,1) -> up to 512 unified VGPRs) carrying THREE
// independent 16-row streams that share a single table set. 48 rows/wave,
// 3 interleavable per-step dependency chains (ILP replaces TLP for latency
// hiding), table cost per row cut 3x. Per-stream math is bitwise identical
// to the 632us R8 kernel (scaled limbs, 4-deep accB chain, DS butterfly
// reduce) so absmax is unchanged and the delta is pure restructure.

#define NSTEPS 19
#define NS 3   // independent 16-row streams per wave

typedef _Float16 half8   __attribute__((ext_vector_type(8)));
typedef _Float16 half2v  __attribute__((ext_vector_type(2)));
typedef float    float2v __attribute__((ext_vector_type(2)));
typedef float    float4v __attribute__((ext_vector_type(4)));

__device__ __forceinline__ half2v pkrtz(float a, float b) {
    return __builtin_bit_cast(half2v, __builtin_amdgcn_cvt_pkrtz(a, b));
}
__device__ __forceinline__ float swz_xor16(float v) {
    // BitMode: and=0x1F, or=0, xor=16 -> lane' = lane ^ 16 (within 32-group)
    int r = __builtin_amdgcn_ds_swizzle(__builtin_bit_cast(int, v), 0x401F);
    return __builtin_bit_cast(float, r);
}
__device__ __forceinline__ float2v lo2(float4v v) {
    return __builtin_shufflevector(v, v, 0, 1);
}
__device__ __forceinline__ float2v hi2(float4v v) {
    return __builtin_shufflevector(v, v, 2, 3);
}

__global__ __launch_bounds__(64, 1)
void program_kernel(const float* __restrict__ x,
                    const float* __restrict__ W1,
                    const float* __restrict__ b1,
                    const float* __restrict__ W2,
                    const float* __restrict__ b2,
                    const float* __restrict__ W3,
                    const float* __restrict__ b3,
                    float* __restrict__ out,
                    int B) {
    const int lane   = threadIdx.x & 63;
    const int lanelo = lane & 15;   // m: batch row within each 16-row tile
    const int q8     = lane >> 4;   // k-slice / replica group 0..3

    int myRow[NS], rowLd[NS];
    #pragma unroll
    for (int S = 0; S < NS; ++S) {
        myRow[S] = blockIdx.x * (16 * NS) + S * 16 + lanelo;
        rowLd[S] = myRow[S] < B ? myRow[S] : (B - 1);
    }

    // ---- w1 tables as pairs (VGPR, shared by all streams) ----
    float2v w1a[8], w1b[8], b1v[8];
    #pragma unroll
    for (int kf = 0; kf < 2; ++kf) {
        const int k0 = kf * 32 + q8 * 8;
        const float2v* a = (const float2v*)(W1 + k0);
        const float2v* bb = (const float2v*)(W1 + 64 + k0);
        const float2v* bv = (const float2v*)(b1 + k0);
        #pragma unroll
        for (int i = 0; i < 4; ++i) {
            w1a[kf * 4 + i] = a[i];
            w1b[kf * 4 + i] = bb[i];
            b1v[kf * 4 + i] = bv[i];
        }
    }

    // ---- W2^T limb A-frags (MFMA-only; AGPR-eligible; shared) ----
    half8 Wh[2][4], Wl[2][4];
    #pragma unroll
    for (int kf = 0; kf < 2; ++kf) {
        #pragma unroll
        for (int t = 0; t < 4; ++t) {
            half8 bh, bl;
            #pragma unroll
            for (int j = 0; j < 8; ++j) {
                const float w =
                    W2[(kf * 32 + q8 * 8 + j) * 64 + t * 16 + lanelo];
                const _Float16 wh = (_Float16)w;                       // RNE
                const _Float16 wl = (_Float16)((w - (float)wh) * 4096.0f);
                bh[j] = wh;
                bl[j] = wl;
            }
            Wh[kf][t] = bh;
            Wl[kf][t] = bl;
        }
    }

    // ---- b2 C-init frags (MFMA-C only; shared) ----
    float4v b2f[4];
    #pragma unroll
    for (int t = 0; t < 4; ++t) {
        const int n = t * 16 + q8 * 4;
        b2f[t] = (float4v){b2[n], b2[n + 1], b2[n + 2], b2[n + 3]};
    }

    // ---- W3 difference tables (VGPR; shared): n = 16t+4*q8+r, pairs ----
    float2v d10[8], d20[8];
    #pragma unroll
    for (int p = 0; p < 8; ++p) {
        const int n0 = (p >> 1) * 16 + q8 * 4 + (p & 1) * 2;
        const float w00 = W3[n0 * 3 + 0],       w01 = W3[n0 * 3 + 1];
        const float w02 = W3[n0 * 3 + 2];
        const float w10 = W3[(n0 + 1) * 3 + 0], w11 = W3[(n0 + 1) * 3 + 1];
        const float w12 = W3[(n0 + 1) * 3 + 2];
        d10[p] = (float2v){w01 - w00, w11 - w10};
        d20[p] = (float2v){w02 - w00, w12 - w10};
    }
    const float b3v0 = b3[0];
    const float db10 = b3[1] - b3[0];
    const float db20 = b3[2] - b3[0];

    // ---- initial row state per stream (4x replicated across q8 groups) ----
    float pos[NS], fwd[NS], c5[NS];
    #pragma unroll
    for (int S = 0; S < NS; ++S) {
        const float* xr = x + (size_t)rowLd[S] * 6;
        pos[S] = xr[0];
        fwd[S] = xr[1];
        c5[S]  = xr[5];
    }

    const float4v zf = {0.f, 0.f, 0.f, 0.f};
    const float2v z2 = {0.f, 0.f};
    const float2v kinv = {1.0f / 4096.0f, 1.0f / 4096.0f};
    float l0[NS], l1[NS], l2[NS];
    #pragma unroll
    for (int S = 0; S < NS; ++S) { l0[S] = l1[S] = l2[S] = 0.f; }

    #pragma unroll 1
    for (int step = 0; step < NSTEPS; ++step) {
        // ---- layer 1 (packed) + 2-limb split -> B-frag limbs, all streams ----
        half8 Hh[NS][2], Hl[NS][2];
        #pragma unroll
        for (int S = 0; S < NS; ++S) {
            const float2v posp = {pos[S], pos[S]}, fwdp = {fwd[S], fwd[S]};
            #pragma unroll
            for (int kf = 0; kf < 2; ++kf) {
                union { half8 v; half2v h2[4]; } uh, ul;
                #pragma unroll
                for (int p = 0; p < 4; ++p) {
                    const int e = kf * 4 + p;
                    float2v z = __builtin_elementwise_fma(fwdp, w1b[e], b1v[e]);
                    z = __builtin_elementwise_fma(posp, w1a[e], z);
                    const float2v hp = __builtin_elementwise_max(z, z2);
                    uh.h2[p] = pkrtz(hp[0], hp[1]);
                    // residuals (hi-half f16 extract folds into v_fma_mix)
                    const float r0 = fmaf((float)uh.h2[p][0], -1.0f, hp[0]);
                    const float r1 = fmaf((float)uh.h2[p][1], -1.0f, hp[1]);
                    const float2v rp = (float2v){r0, r1} * 4096.0f;  // pk_mul
                    ul.h2[p] = pkrtz(rp[0], rp[1]);
                }
                Hh[S][kf] = uh.v;
                Hl[S][kf] = ul.v;
            }
        }

        // ---- layer 2 via MFMA, all streams (R8 chain order per stream) ----
        float4v accA[NS][4], accB[NS][4];
        #pragma unroll
        for (int S = 0; S < NS; ++S) {
            #pragma unroll
            for (int t = 0; t < 4; ++t) {
                accB[S][t] = __builtin_amdgcn_mfma_f32_16x16x32_f16(
                    Wl[0][t], Hh[S][0], zf, 0, 0, 0);
                accB[S][t] = __builtin_amdgcn_mfma_f32_16x16x32_f16(
                    Wh[0][t], Hl[S][0], accB[S][t], 0, 0, 0);
                accB[S][t] = __builtin_amdgcn_mfma_f32_16x16x32_f16(
                    Wl[1][t], Hh[S][1], accB[S][t], 0, 0, 0);
                accB[S][t] = __builtin_amdgcn_mfma_f32_16x16x32_f16(
                    Wh[1][t], Hl[S][1], accB[S][t], 0, 0, 0);
                accA[S][t] = __builtin_amdgcn_mfma_f32_16x16x32_f16(
                    Wh[0][t], Hh[S][0], b2f[t], 0, 0, 0);
                accA[S][t] = __builtin_amdgcn_mfma_f32_16x16x32_f16(
                    Wh[1][t], Hh[S][1], accA[S][t], 0, 0, 0);
            }
        }

        // ---- per stream: combine, dots, reduce, decision ----
        #pragma unroll
        for (int S = 0; S < NS; ++S) {
            float2v h2p[8];
            #pragma unroll
            for (int t = 0; t < 4; ++t) {
                h2p[2 * t] = __builtin_elementwise_max(
                    __builtin_elementwise_fma(lo2(accB[S][t]), kinv,
                                              lo2(accA[S][t])),
                    z2);
                h2p[2 * t + 1] = __builtin_elementwise_max(
                    __builtin_elementwise_fma(hi2(accB[S][t]), kinv,
                                              hi2(accA[S][t])),
                    z2);
            }

            float2v s1 = z2, s2 = z2;
            #pragma unroll
            for (int p = 0; p < 8; ++p) {
                s1 = __builtin_elementwise_fma(h2p[p], d10[p], s1);
                s2 = __builtin_elementwise_fma(h2p[p], d20[p], s2);
            }
            float g10 = s1[0] + s1[1];
            float g20 = s2[0] + s2[1];
            g10 += swz_xor16(g10);
            g20 += swz_xor16(g20);
            g10 += __shfl_xor(g10, 32, 64);
            g20 += __shfl_xor(g20, 32, 64);
            g10 += db10;   // = l1 - l0
            g20 += db20;   // = l2 - l0

            // ---- last step: reconstruct full logits for the output probs ----
            if (step == NSTEPS - 1) {
                float2v s0 = z2;
                #pragma unroll
                for (int p = 0; p < 8; ++p) {
                    const int n0 = (p >> 1) * 16 + q8 * 4 + (p & 1) * 2;
                    const float2v w30 = {W3[n0 * 3], W3[(n0 + 1) * 3]};
                    s0 = __builtin_elementwise_fma(h2p[p], w30, s0);
                }
                float t0 = s0[0] + s0[1];
                t0 += swz_xor16(t0);
                t0 += __shfl_xor(t0, 32, 64);
                l0[S] = t0 + b3v0;
                l1[S] = l0[S] + g10;
                l2[S] = l0[S] + g20;
            }

            // ---- decision: l2 > max(l0,l1) <=> g20 > max(0,g10);
            //      l1 > l0 <=> g10 > 0 (first-max-wins preserved) ----
            const float delta =
                (g20 > fmaxf(0.f, g10)) ? 1.0f : ((g10 > 0.f) ? 0.0f : -1.0f);
            pos[S] += delta;
            fwd[S] += 1.0f;
        }
    }

    // ---- epilogue: all lanes have their row's logits; q8==0 stores ----
    #pragma unroll
    for (int S = 0; S < NS; ++S) {
        if (q8 == 0 && myRow[S] < B) {
            const float p0 = 1.f / (1.f + __expf(-l0[S]));
            const float p1 = 1.f / (1.f + __expf(-l1[S]));
            const float p2 = 1.f / (1.f + __expf(-l2[S]));
            float2* o = (float2*)(out + (size_t)myRow[S] * 6);
            o[0] = make_float2(pos[S], fwd[S]);
            o[1] = make_float2(p0, p1);
            o[2] = make_float2(p2, c5[S] + (float)NSTEPS);
        }
    }
}

extern "C" void kernel_launch(void* const* d_in, const int* in_sizes, int n_in,
                              void* d_out, int out_size, void* d_ws, size_t ws_size,
                              hipStream_t stream) {
    const float* x  = (const float*)d_in[0];
    const float* W1 = (const float*)d_in[1];
    const float* b1 = (const float*)d_in[2];
    const float* W2 = (const float*)d_in[3];
    const float* b2 = (const float*)d_in[4];
    const float* W3 = (const float*)d_in[5];
    const float* b3 = (const float*)d_in[6];
    float* out = (float*)d_out;

    const int B = in_sizes[0] / 6;                  // 1048576
    const int rowsPerBlock = 16 * NS;               // 48 rows (3 tiles x 16)
    const int nBlocks = (B + rowsPerBlock - 1) / rowsPerBlock;

    program_kernel<<<nBlocks, 64, 0, stream>>>(
        x, W1, b1, W2, b2, W3, b3, out, B);
}

// Round 3
// 639.868 us; speedup vs baseline: 1.2531x; 1.2531x over previous
//
#include <hip/hip_runtime.h>
#include <math.h>

// Program interpreter: B=1M rows, 19 steps of MLP(2->64->64->3) + argmax walk.
// fp32 emulated on f16 MFMA, 2-limb splits (lo limb scaled 2^12, RTZ pack).
//
// R11: break the wave phase-lock. Busy-cycle accounting across R8/R9/R10
// shows VALU-busy (~441us) + MFMA-busy (~226us) ~= wall (684us): the two
// co-resident waves per SIMD run identical code, phase-lock under round-robin
// issue, and the VALU and matrix pipes never overlap. Fix: s_setprio(1)
// around the 24-MFMA cluster (T5). The wave entering the MFMA region
// preempts the issue port, finishes its matrix work while the peer wave's
// VALU is deferred, then yields -> sustained anti-phase, pipes overlap.
// Math is bitwise identical to the 632us R8 kernel (scaled limbs, 4-deep
// accB chain, DS butterfly reduce): absmax must stay exactly 0.00390625.

#define NSTEPS 19

typedef _Float16 half8   __attribute__((ext_vector_type(8)));
typedef _Float16 half2v  __attribute__((ext_vector_type(2)));
typedef float    float2v __attribute__((ext_vector_type(2)));
typedef float    float4v __attribute__((ext_vector_type(4)));

__device__ __forceinline__ half2v pkrtz(float a, float b) {
    return __builtin_bit_cast(half2v, __builtin_amdgcn_cvt_pkrtz(a, b));
}
__device__ __forceinline__ float swz_xor16(float v) {
    // BitMode: and=0x1F, or=0, xor=16 -> lane' = lane ^ 16 (within 32-group)
    int r = __builtin_amdgcn_ds_swizzle(__builtin_bit_cast(int, v), 0x401F);
    return __builtin_bit_cast(float, r);
}
__device__ __forceinline__ float2v lo2(float4v v) {
    return __builtin_shufflevector(v, v, 0, 1);
}
__device__ __forceinline__ float2v hi2(float4v v) {
    return __builtin_shufflevector(v, v, 2, 3);
}

__global__ __launch_bounds__(256, 2)
void program_kernel(const float* __restrict__ x,
                    const float* __restrict__ W1,
                    const float* __restrict__ b1,
                    const float* __restrict__ W2,
                    const float* __restrict__ b2,
                    const float* __restrict__ W3,
                    const float* __restrict__ b3,
                    float* __restrict__ out,
                    int B) {
    const int tid    = threadIdx.x;
    const int lane   = tid & 63;
    const int wave   = tid >> 6;
    const int lanelo = lane & 15;   // m: my batch row within the tile
    const int q8     = lane >> 4;   // k-slice / replica group 0..3
    const int myRow  = blockIdx.x * 64 + wave * 16 + lanelo;
    const int rowLd  = myRow < B ? myRow : (B - 1);

    // ---- w1 tables as pairs (VGPR): pair i of kf-half: k = kf*32+q8*8+2i ----
    float2v w1a[8], w1b[8], b1v[8];
    #pragma unroll
    for (int kf = 0; kf < 2; ++kf) {
        const int k0 = kf * 32 + q8 * 8;
        const float2v* a = (const float2v*)(W1 + k0);
        const float2v* bb = (const float2v*)(W1 + 64 + k0);
        const float2v* bv = (const float2v*)(b1 + k0);
        #pragma unroll
        for (int i = 0; i < 4; ++i) {
            w1a[kf * 4 + i] = a[i];
            w1b[kf * 4 + i] = bb[i];
            b1v[kf * 4 + i] = bv[i];
        }
    }

    // ---- W2^T limb A-frags (MFMA-only; AGPR-eligible) ----
    half8 Wh[2][4], Wl[2][4];
    #pragma unroll
    for (int kf = 0; kf < 2; ++kf) {
        #pragma unroll
        for (int t = 0; t < 4; ++t) {
            half8 bh, bl;
            #pragma unroll
            for (int j = 0; j < 8; ++j) {
                const float w =
                    W2[(kf * 32 + q8 * 8 + j) * 64 + t * 16 + lanelo];
                const _Float16 wh = (_Float16)w;                       // RNE
                const _Float16 wl = (_Float16)((w - (float)wh) * 4096.0f);
                bh[j] = wh;
                bl[j] = wl;
            }
            Wh[kf][t] = bh;
            Wl[kf][t] = bl;
        }
    }

    // ---- b2 C-init frags (MFMA-C only) ----
    float4v b2f[4];
    #pragma unroll
    for (int t = 0; t < 4; ++t) {
        const int n = t * 16 + q8 * 4;
        b2f[t] = (float4v){b2[n], b2[n + 1], b2[n + 2], b2[n + 3]};
    }

    // ---- W3 difference tables (VGPR): my n-set n = 16t+4*q8+r, pairs ----
    float2v d10[8], d20[8];
    #pragma unroll
    for (int p = 0; p < 8; ++p) {
        const int n0 = (p >> 1) * 16 + q8 * 4 + (p & 1) * 2;
        const float w00 = W3[n0 * 3 + 0],       w01 = W3[n0 * 3 + 1];
        const float w02 = W3[n0 * 3 + 2];
        const float w10 = W3[(n0 + 1) * 3 + 0], w11 = W3[(n0 + 1) * 3 + 1];
        const float w12 = W3[(n0 + 1) * 3 + 2];
        d10[p] = (float2v){w01 - w00, w11 - w10};
        d20[p] = (float2v){w02 - w00, w12 - w10};
    }
    const float b3v0 = b3[0];
    const float db10 = b3[1] - b3[0];
    const float db20 = b3[2] - b3[0];

    // ---- initial row state (4x replicated across q8 groups) ----
    float pos, fwd, c5;
    {
        const float* xr = x + (size_t)rowLd * 6;
        pos = xr[0];
        fwd = xr[1];
        c5  = xr[5];
    }

    const float4v zf = {0.f, 0.f, 0.f, 0.f};
    const float2v z2 = {0.f, 0.f};
    const float2v kinv = {1.0f / 4096.0f, 1.0f / 4096.0f};
    float l0 = 0.f, l1 = 0.f, l2 = 0.f;

    #pragma unroll 1
    for (int step = 0; step < NSTEPS; ++step) {
        // ---- layer 1 (packed) + 2-limb split -> B-frag limbs ----
        const float2v posp = {pos, pos}, fwdp = {fwd, fwd};
        half8 Hh[2], Hl[2];
        #pragma unroll
        for (int kf = 0; kf < 2; ++kf) {
            union { half8 v; half2v h2[4]; } uh, ul;
            #pragma unroll
            for (int p = 0; p < 4; ++p) {
                const int e = kf * 4 + p;
                float2v z = __builtin_elementwise_fma(fwdp, w1b[e], b1v[e]);
                z = __builtin_elementwise_fma(posp, w1a[e], z);
                const float2v hp = __builtin_elementwise_max(z, z2);
                uh.h2[p] = pkrtz(hp[0], hp[1]);
                // residuals (hi-half f16 extract folds into v_fma_mix)
                const float r0 = fmaf((float)uh.h2[p][0], -1.0f, hp[0]);
                const float r1 = fmaf((float)uh.h2[p][1], -1.0f, hp[1]);
                const float2v rp = (float2v){r0, r1} * 4096.0f;  // pk_mul
                ul.h2[p] = pkrtz(rp[0], rp[1]);
            }
            Hh[kf] = uh.v;
            Hl[kf] = ul.v;
        }

        // ---- layer 2 via MFMA (same chain/order as R8), priority-boosted ----
        // T5: the wave entering this pure-MFMA cluster takes the issue port;
        // the peer wave on the SIMD runs its VALU phase meanwhile.
        __builtin_amdgcn_s_setprio(1);
        float4v accA[4], accB[4];
        #pragma unroll
        for (int t = 0; t < 4; ++t) {
            accB[t] = __builtin_amdgcn_mfma_f32_16x16x32_f16(
                Wl[0][t], Hh[0], zf, 0, 0, 0);
            accB[t] = __builtin_amdgcn_mfma_f32_16x16x32_f16(
                Wh[0][t], Hl[0], accB[t], 0, 0, 0);
            accB[t] = __builtin_amdgcn_mfma_f32_16x16x32_f16(
                Wl[1][t], Hh[1], accB[t], 0, 0, 0);
            accB[t] = __builtin_amdgcn_mfma_f32_16x16x32_f16(
                Wh[1][t], Hl[1], accB[t], 0, 0, 0);
            accA[t] = __builtin_amdgcn_mfma_f32_16x16x32_f16(
                Wh[0][t], Hh[0], b2f[t], 0, 0, 0);
            accA[t] = __builtin_amdgcn_mfma_f32_16x16x32_f16(
                Wh[1][t], Hh[1], accA[t], 0, 0, 0);
        }
        __builtin_amdgcn_s_setprio(0);

        // ---- h2 (packed combine+relu) ----
        float2v h2p[8];
        #pragma unroll
        for (int t = 0; t < 4; ++t) {
            h2p[2 * t] = __builtin_elementwise_max(
                __builtin_elementwise_fma(lo2(accB[t]), kinv, lo2(accA[t])),
                z2);
            h2p[2 * t + 1] = __builtin_elementwise_max(
                __builtin_elementwise_fma(hi2(accB[t]), kinv, hi2(accA[t])),
                z2);
        }

        // ---- difference dots (packed) + cross-replica reduce ----
        float2v s1 = z2, s2 = z2;
        #pragma unroll
        for (int p = 0; p < 8; ++p) {
            s1 = __builtin_elementwise_fma(h2p[p], d10[p], s1);
            s2 = __builtin_elementwise_fma(h2p[p], d20[p], s2);
        }
        float g10 = s1[0] + s1[1];
        float g20 = s2[0] + s2[1];
        g10 += swz_xor16(g10);
        g20 += swz_xor16(g20);
        g10 += __shfl_xor(g10, 32, 64);
        g20 += __shfl_xor(g20, 32, 64);
        g10 += db10;   // = l1 - l0
        g20 += db20;   // = l2 - l0

        // ---- last step: reconstruct full logits for the output probs ----
        if (step == NSTEPS - 1) {
            float2v s0 = z2;
            #pragma unroll
            for (int p = 0; p < 8; ++p) {
                const int n0 = (p >> 1) * 16 + q8 * 4 + (p & 1) * 2;
                const float2v w30 = {W3[n0 * 3], W3[(n0 + 1) * 3]};
                s0 = __builtin_elementwise_fma(h2p[p], w30, s0);
            }
            float t0 = s0[0] + s0[1];
            t0 += swz_xor16(t0);
            t0 += __shfl_xor(t0, 32, 64);
            l0 = t0 + b3v0;
            l1 = l0 + g10;
            l2 = l0 + g20;
        }

        // ---- decision: l2 > max(l0,l1) <=> g20 > max(0,g10);
        //      l1 > l0 <=> g10 > 0 (first-max-wins preserved) ----
        const float delta =
            (g20 > fmaxf(0.f, g10)) ? 1.0f : ((g10 > 0.f) ? 0.0f : -1.0f);
        pos += delta;
        fwd += 1.0f;
    }

    // ---- epilogue: all lanes have their row's logits; q8==0 stores ----
    if (q8 == 0 && myRow < B) {
        const float p0 = 1.f / (1.f + __expf(-l0));
        const float p1 = 1.f / (1.f + __expf(-l1));
        const float p2 = 1.f / (1.f + __expf(-l2));
        float2* o = (float2*)(out + (size_t)myRow * 6);
        o[0] = make_float2(pos, fwd);
        o[1] = make_float2(p0, p1);
        o[2] = make_float2(p2, c5 + (float)NSTEPS);
    }
}

extern "C" void kernel_launch(void* const* d_in, const int* in_sizes, int n_in,
                              void* d_out, int out_size, void* d_ws, size_t ws_size,
                              hipStream_t stream) {
    const float* x  = (const float*)d_in[0];
    const float* W1 = (const float*)d_in[1];
    const float* b1 = (const float*)d_in[2];
    const float* W2 = (const float*)d_in[3];
    const float* b2 = (const float*)d_in[4];
    const float* W3 = (const float*)d_in[5];
    const float* b3 = (const float*)d_in[6];
    float* out = (float*)d_out;

    const int B = in_sizes[0] / 6;              // 1048576
    const int nBlocks = (B + 63) / 64;          // 64 rows/block (4 waves x 16)

    program_kernel<<<nBlocks, 256, 0, stream>>>(
        x, W1, b1, W2, b2, W3, b3, out, B);
}